// Round 1
// baseline (45.563 us; speedup 1.0000x reference)
//
#include <hip/hip_runtime.h>

// SparseCSREncoder roundtrip == elementwise threshold mask:
//   out[i] = (|x[i]| > 0.5f) ? x[i] : 0.0f
// Memory-bound: 128 MiB in + 128 MiB out. float4 loads/stores, grid-stride.

#define THRESHOLD 0.5f

__global__ __launch_bounds__(256) void sparse_mask_kernel(
    const float4* __restrict__ x, float4* __restrict__ out, int n4) {
    int idx = blockIdx.x * blockDim.x + threadIdx.x;
    int stride = gridDim.x * blockDim.x;
    for (int i = idx; i < n4; i += stride) {
        float4 v = x[i];
        v.x = (fabsf(v.x) > THRESHOLD) ? v.x : 0.0f;
        v.y = (fabsf(v.y) > THRESHOLD) ? v.y : 0.0f;
        v.z = (fabsf(v.z) > THRESHOLD) ? v.z : 0.0f;
        v.w = (fabsf(v.w) > THRESHOLD) ? v.w : 0.0f;
        out[i] = v;
    }
}

extern "C" void kernel_launch(void* const* d_in, const int* in_sizes, int n_in,
                              void* d_out, int out_size, void* d_ws, size_t ws_size,
                              hipStream_t stream) {
    const float* x = (const float*)d_in[0];
    float* out = (float*)d_out;
    int n = in_sizes[0];          // 33554432, divisible by 4
    int n4 = n / 4;

    const int block = 256;
    // Cap grid at 2048 blocks (256 CUs x 8 blocks), grid-stride the rest.
    int grid = (n4 + block - 1) / block;
    if (grid > 2048) grid = 2048;

    sparse_mask_kernel<<<grid, block, 0, stream>>>(
        (const float4*)x, (float4*)out, n4);
}